// Round 6
// baseline (44.712 us; speedup 1.0000x reference)
//
#include <hip/hip_runtime.h>

#define SMOOTHF 0.001f
#define DICE_WF 0.8f

constexpr int N_B = 16, N_C = 3, N_H = 512, N_W = 512;
constexpr int SLICES    = N_B * N_C;          // 48
constexpr int ELEMS     = N_H * N_W;          // 262144 elements per (b,c) slice
constexpr int TPB       = 256;
constexpr int BPS       = 32;                 // blocks per slice
constexpr int NBLK      = SLICES * BPS;       // 1536 blocks
constexpr int V4_SLICE  = ELEMS / 4;          // 65536 float4 per slice
constexpr int V4_BLOCK  = V4_SLICE / BPS;     // 2048 float4 per block
constexpr int V4_THREAD = V4_BLOCK / TPB;     // 8 float4 per thread

// ws layout (floats/uints), zeroed by a memset node each call:
//   [0 .. 239]   sums[comp][slice]  (5 x 48, SoA)
//   [240 .. 287] per-slice tickets (unsigned)
//   [288]        global finisher ticket (unsigned)
//   [289]        loss accumulator (float)
constexpr int WS_WORDS = 290;

// Five linear accumulators (targets are exactly {0,1}):
//   sp = Σ sigmoid(x)   pt = Σ sigmoid(x)·t   st = Σ t
//   sd = Σ (x−t)²       sdt = Σ (x−t)²·t
struct Acc { float sp, pt, st, sd, sdt; };

__device__ __forceinline__ void acc1(float x, float t, Acc& a) {
    float e  = __expf(-x);
    float p  = __builtin_amdgcn_rcpf(1.0f + e);  // sigmoid via v_rcp
    float d  = x - t;
    float d2 = d * d;
    a.sp += p;
    a.pt  = fmaf(p, t, a.pt);
    a.st += t;
    a.sd += d2;
    a.sdt = fmaf(d2, t, a.sdt);
}

__device__ __forceinline__ void waveReduce5(Acc& a) {
    #pragma unroll
    for (int off = 32; off > 0; off >>= 1) {
        a.sp  += __shfl_down(a.sp,  off, 64);
        a.pt  += __shfl_down(a.pt,  off, 64);
        a.st  += __shfl_down(a.st,  off, 64);
        a.sd  += __shfl_down(a.sd,  off, 64);
        a.sdt += __shfl_down(a.sdt, off, 64);
    }
}

// Single kernel. All cross-block data moves via device-scope atomics (the
// cross-XCD coherence point), so NO __threadfence / L2 flush is needed —
// only vmcnt drains of this thread's own atomic ops (R3's lesson).
__global__ __launch_bounds__(TPB) void fused(const float4* __restrict__ lg,
                                             const float4* __restrict__ tg,
                                             float* __restrict__ ws,
                                             float* __restrict__ out) {
    const int blk   = blockIdx.x;
    const int tid   = (int)threadIdx.x;
    const int slice = blk >> 5;                 // BPS = 32
    const int base  = blk * V4_BLOCK + tid;

    Acc a{0.f, 0.f, 0.f, 0.f, 0.f};
    #pragma unroll
    for (int k = 0; k < V4_THREAD; ++k) {       // R2's proven streaming loop
        float4 x4 = lg[base + k * TPB];
        float4 t4 = tg[base + k * TPB];
        acc1(x4.x, t4.x, a); acc1(x4.y, t4.y, a);
        acc1(x4.z, t4.z, a); acc1(x4.w, t4.w, a);
    }
    waveReduce5(a);

    __shared__ float red[TPB / 64][5];
    const int wave = tid >> 6;
    if ((tid & 63) == 0) {
        red[wave][0] = a.sp; red[wave][1] = a.pt; red[wave][2] = a.st;
        red[wave][3] = a.sd; red[wave][4] = a.sdt;
    }
    __syncthreads();
    if (tid != 0) return;

    float v[5];
    #pragma unroll
    for (int c = 0; c < 5; ++c)
        v[c] = ((red[0][c] + red[1][c]) + (red[2][c] + red[3][c]));

    float*    sums    = ws;                          // [5][48]
    unsigned* tickets = (unsigned*)(ws + 240);       // [48]
    unsigned* gticket = (unsigned*)(ws + 288);
    float*    lossacc = ws + 289;

    // Deposit partials via atomics; keep returns alive so the returning
    // (sc0) form is emitted and vmcnt tracks full RMW completion.
    float r0 = atomicAdd(&sums[0 * SLICES + slice], v[0]);
    float r1 = atomicAdd(&sums[1 * SLICES + slice], v[1]);
    float r2 = atomicAdd(&sums[2 * SLICES + slice], v[2]);
    float r3 = atomicAdd(&sums[3 * SLICES + slice], v[3]);
    float r4 = atomicAdd(&sums[4 * SLICES + slice], v[4]);
    asm volatile("" :: "v"(r0), "v"(r1), "v"(r2), "v"(r3), "v"(r4));
    asm volatile("s_waitcnt vmcnt(0)" ::: "memory");  // my adds committed

    unsigned t = atomicAdd(&tickets[slice], 1u);
    if (t != (unsigned)(BPS - 1)) return;

    // ---- slice finisher: all 32 blocks' adds for this slice committed ----
    float sp  = atomicAdd(&sums[0 * SLICES + slice], 0.0f);
    float pt  = atomicAdd(&sums[1 * SLICES + slice], 0.0f);
    float st  = atomicAdd(&sums[2 * SLICES + slice], 0.0f);
    float sd  = atomicAdd(&sums[3 * SLICES + slice], 0.0f);
    float sdt = atomicAdd(&sums[4 * SLICES + slice], 0.0f);

    float dice = (2.0f * pt + SMOOTHF) / (sp + st + SMOOTHF);
    float cp = st, cn = (float)ELEMS - st;
    float s1 = sdt, s0 = sd - sdt;
    float mp = (cp > 0.f) ? s1 / fmaxf(cp, 1.f) : 0.f;
    float mn = (cn > 0.f) ? s0 / fmaxf(cn, 1.f) : 0.f;
    // loss = 0.8 + Σ_s (−0.8·dice_s + 0.2·(mp_s+mn_s)) / 48
    float contrib = (-DICE_WF * dice + (1.0f - DICE_WF) * (mp + mn)) / (float)SLICES;

    float rl = atomicAdd(lossacc, contrib);
    asm volatile("" :: "v"(rl));
    asm volatile("s_waitcnt vmcnt(0)" ::: "memory");  // my contrib committed

    unsigned g = atomicAdd(gticket, 1u);
    if (g == (unsigned)(SLICES - 1)) {
        // ---- global finisher: all 48 contributions committed ----
        float total = atomicAdd(lossacc, 0.0f);
        out[0] = DICE_WF + total;                 // plain store, overwrites stale
    }
}

extern "C" void kernel_launch(void* const* d_in, const int* in_sizes, int n_in,
                              void* d_out, int out_size, void* d_ws, size_t ws_size,
                              hipStream_t stream) {
    const float4* lg = (const float4*)d_in[0];
    const float4* tg = (const float4*)d_in[1];
    float* out = (float*)d_out;
    float* ws  = (float*)d_ws;
    hipMemsetAsync(ws, 0, WS_WORDS * sizeof(float), stream);  // graph-safe
    fused<<<NBLK, TPB, 0, stream>>>(lg, tg, ws, out);
}

// Round 7
// 38.749 us; speedup vs baseline: 1.1539x; 1.1539x over previous
//
#include <hip/hip_runtime.h>

#define SMOOTHF 0.001f
#define DICE_WF 0.8f

constexpr int N_B = 16, N_C = 3, N_H = 512, N_W = 512;
constexpr int SLICES    = N_B * N_C;          // 48
constexpr int ELEMS     = N_H * N_W;          // 262144 elements per (b,c) slice
constexpr int TPB       = 256;
constexpr int BPS       = 32;                 // blocks per slice
constexpr int NBLK      = SLICES * BPS;       // 1536 blocks
constexpr int V4_SLICE  = ELEMS / 4;          // 65536 float4 per slice
constexpr int V4_BLOCK  = V4_SLICE / BPS;     // 2048 float4 per block
constexpr int V4_THREAD = V4_BLOCK / TPB;     // 8 float4 per thread

// ws layout (4-byte words), zeroed by a memset node each call:
//   [0 .. 7679]     part[c*NBLK + blk]   per-block partials (UNIQUE slots)
//   [7680 .. 7727]  contrib[slice]       per-slice loss contribution
//   [7728 .. 7775]  tickets[slice]       (unsigned, <=32 RMWs each)
//   [7776]          gticket              (unsigned, 48 RMWs)
constexpr int OFF_CONTRIB = 5 * NBLK;         // 7680
constexpr int OFF_TICKETS = OFF_CONTRIB + SLICES;
constexpr int OFF_GTICKET = OFF_TICKETS + SLICES;
constexpr int WS_WORDS    = OFF_GTICKET + 1;  // 7777

// Five linear accumulators (targets are exactly {0,1}):
//   sp = Σ sigmoid(x)   pt = Σ sigmoid(x)·t   st = Σ t
//   sd = Σ (x−t)²       sdt = Σ (x−t)²·t
struct Acc { float sp, pt, st, sd, sdt; };

__device__ __forceinline__ void acc1(float x, float t, Acc& a) {
    float e  = __expf(-x);
    float p  = __builtin_amdgcn_rcpf(1.0f + e);  // sigmoid via v_rcp
    float d  = x - t;
    float d2 = d * d;
    a.sp += p;
    a.pt  = fmaf(p, t, a.pt);
    a.st += t;
    a.sd += d2;
    a.sdt = fmaf(d2, t, a.sdt);
}

__device__ __forceinline__ void waveReduce5(Acc& a) {
    #pragma unroll
    for (int off = 32; off > 0; off >>= 1) {
        a.sp  += __shfl_down(a.sp,  off, 64);
        a.pt  += __shfl_down(a.pt,  off, 64);
        a.st  += __shfl_down(a.st,  off, 64);
        a.sd  += __shfl_down(a.sd,  off, 64);
        a.sdt += __shfl_down(a.sdt, off, 64);
    }
}

// Single kernel, contention-free protocol:
//  - deposits: returning atomicAdd into UNIQUE zeroed slots (exact store at
//    the device coherence point; no same-address FP contention — R6's bug)
//  - visibility: vmcnt(0) drains own atomics before taking a ticket
//  - tickets: int atomics, <=32 (per-slice) / 48 (global) RMWs per address
//  - all folds in fixed index order => bit-deterministic
__global__ __launch_bounds__(TPB) void fused(const float4* __restrict__ lg,
                                             const float4* __restrict__ tg,
                                             float* __restrict__ ws,
                                             float* __restrict__ out) {
    const int blk   = blockIdx.x;
    const int tid   = (int)threadIdx.x;
    const int slice = blk >> 5;                 // BPS = 32
    const int base  = blk * V4_BLOCK + tid;

    float*    part    = ws;
    float*    contrib = ws + OFF_CONTRIB;
    unsigned* tickets = (unsigned*)(ws + OFF_TICKETS);
    unsigned* gticket = (unsigned*)(ws + OFF_GTICKET);

    Acc a{0.f, 0.f, 0.f, 0.f, 0.f};
    #pragma unroll
    for (int k = 0; k < V4_THREAD; ++k) {       // R2's proven streaming loop
        float4 x4 = lg[base + k * TPB];
        float4 t4 = tg[base + k * TPB];
        acc1(x4.x, t4.x, a); acc1(x4.y, t4.y, a);
        acc1(x4.z, t4.z, a); acc1(x4.w, t4.w, a);
    }
    waveReduce5(a);

    __shared__ float red[TPB / 64][5];
    __shared__ int   s_role, s_grole;
    const int wave = tid >> 6;
    if ((tid & 63) == 0) {
        red[wave][0] = a.sp; red[wave][1] = a.pt; red[wave][2] = a.st;
        red[wave][3] = a.sd; red[wave][4] = a.sdt;
    }
    __syncthreads();

    if (tid == 0) {
        float v[5];
        #pragma unroll
        for (int c = 0; c < 5; ++c)
            v[c] = (red[0][c] + red[1][c]) + (red[2][c] + red[3][c]);
        float r0 = atomicAdd(&part[0 * NBLK + blk], v[0]);
        float r1 = atomicAdd(&part[1 * NBLK + blk], v[1]);
        float r2 = atomicAdd(&part[2 * NBLK + blk], v[2]);
        float r3 = atomicAdd(&part[3 * NBLK + blk], v[3]);
        float r4 = atomicAdd(&part[4 * NBLK + blk], v[4]);
        asm volatile("" :: "v"(r0), "v"(r1), "v"(r2), "v"(r3), "v"(r4));
        asm volatile("s_waitcnt vmcnt(0)" ::: "memory");  // adds committed
        unsigned t = atomicAdd(&tickets[slice], 1u);
        s_role = (t == (unsigned)(BPS - 1)) ? 1 : 0;
    }
    __syncthreads();
    if (!s_role) return;                        // uniform per block

    // ---- slice finisher: all 32 deposits for `slice` are committed ----
    __shared__ float fin[5][BPS];
    if (tid < 5 * BPS) {                        // 160 threads, 1 zero-add each
        const int c = tid >> 5, k = tid & 31;
        fin[c][k] = atomicAdd(&part[c * NBLK + (slice << 5) + k], 0.0f);
    }
    __syncthreads();
    if (tid == 0) {
        float s[5];
        #pragma unroll
        for (int c = 0; c < 5; ++c) {
            float acc = 0.f;
            #pragma unroll
            for (int k = 0; k < BPS; ++k) acc += fin[c][k];  // fixed order
            s[c] = acc;
        }
        float sp = s[0], pt = s[1], st = s[2], sd = s[3], sdt = s[4];
        float dice = (2.0f * pt + SMOOTHF) / (sp + st + SMOOTHF);
        float cp = st, cn = (float)ELEMS - st;
        float s1 = sdt, s0 = sd - sdt;
        float mp = (cp > 0.f) ? s1 / fmaxf(cp, 1.f) : 0.f;
        float mn = (cn > 0.f) ? s0 / fmaxf(cn, 1.f) : 0.f;
        // loss = 0.8 + Σ_s (−0.8·dice_s + 0.2·(mp_s+mn_s)) / 48
        float c = (-DICE_WF * dice + (1.0f - DICE_WF) * (mp + mn)) / (float)SLICES;
        float rc = atomicAdd(&contrib[slice], c);   // unique slot
        asm volatile("" :: "v"(rc));
        asm volatile("s_waitcnt vmcnt(0)" ::: "memory");
        unsigned g = atomicAdd(gticket, 1u);
        s_grole = (g == (unsigned)(SLICES - 1)) ? 1 : 0;
    }
    __syncthreads();
    if (!s_grole) return;                       // uniform per block

    // ---- global finisher: all 48 contribs committed ----
    __shared__ float cfin[SLICES];
    if (tid < SLICES) cfin[tid] = atomicAdd(&contrib[tid], 0.0f);
    __syncthreads();
    if (tid == 0) {
        float total = 0.f;
        #pragma unroll
        for (int s = 0; s < SLICES; ++s) total += cfin[s];  // fixed order
        out[0] = DICE_WF + total;               // plain store overwrites stale
    }
}

extern "C" void kernel_launch(void* const* d_in, const int* in_sizes, int n_in,
                              void* d_out, int out_size, void* d_ws, size_t ws_size,
                              hipStream_t stream) {
    const float4* lg = (const float4*)d_in[0];
    const float4* tg = (const float4*)d_in[1];
    float* out = (float*)d_out;
    float* ws  = (float*)d_ws;
    hipMemsetAsync(ws, 0, WS_WORDS * sizeof(float), stream);  // graph-safe
    fused<<<NBLK, TPB, 0, stream>>>(lg, tg, ws, out);
}

// Round 8
// 24.428 us; speedup vs baseline: 1.8304x; 1.5862x over previous
//
#include <hip/hip_runtime.h>

#define SMOOTHF 0.001f
#define DICE_WF 0.8f

constexpr int N_B = 16, N_C = 3, N_H = 512, N_W = 512;
constexpr int SLICES    = N_B * N_C;          // 48
constexpr int ELEMS     = N_H * N_W;          // 262144 elements per (b,c) slice
constexpr int TPB       = 256;
constexpr int BPS       = 64;                 // blocks per slice (R7: 32 -> 64)
constexpr int NBLK      = SLICES * BPS;       // 3072 stage1 blocks
constexpr int V4_SLICE  = ELEMS / 4;          // 65536 float4 per slice
constexpr int V4_BLOCK  = V4_SLICE / BPS;     // 1024 float4 per block
constexpr int V4_THREAD = V4_BLOCK / TPB;     // 4 float4 per thread
constexpr int WS_FLOATS = 5 * NBLK;           // SoA partials: ws[comp][NBLK] (60 KB)

// Five linear accumulators (targets are exactly {0,1}):
//   sp = Σ sigmoid(x)   pt = Σ sigmoid(x)·t   st = Σ t
//   sd = Σ (x−t)²       sdt = Σ (x−t)²·t
// inter = pt, cnt_pos = st, sse_pos = sdt, sse_neg = sd − sdt.
struct Acc { float sp, pt, st, sd, sdt; };

__device__ __forceinline__ void acc1(float x, float t, Acc& a) {
    float e  = __expf(-x);
    float p  = __builtin_amdgcn_rcpf(1.0f + e);  // sigmoid via v_rcp
    float d  = x - t;
    float d2 = d * d;
    a.sp += p;
    a.pt  = fmaf(p, t, a.pt);
    a.st += t;
    a.sd += d2;
    a.sdt = fmaf(d2, t, a.sdt);
}

__device__ __forceinline__ void waveReduce5(Acc& a) {
    #pragma unroll
    for (int off = 32; off > 0; off >>= 1) {
        a.sp  += __shfl_down(a.sp,  off, 64);
        a.pt  += __shfl_down(a.pt,  off, 64);
        a.st  += __shfl_down(a.st,  off, 64);
        a.sd  += __shfl_down(a.sd,  off, 64);
        a.sdt += __shfl_down(a.sdt, off, 64);
    }
}

// Stage 1: thin streaming blocks. All 8 loads (4 lg + 4 tg float4) issued
// before any compute; short epilogue; no fences, no atomics.
__global__ __launch_bounds__(TPB) void stage1(const float4* __restrict__ lg,
                                              const float4* __restrict__ tg,
                                              float* __restrict__ ws) {
    const int blk  = blockIdx.x;
    const int tid  = (int)threadIdx.x;
    const int base = blk * V4_BLOCK + tid;

    float4 xv[V4_THREAD], tv[V4_THREAD];
    #pragma unroll
    for (int k = 0; k < V4_THREAD; ++k) xv[k] = lg[base + k * TPB];
    #pragma unroll
    for (int k = 0; k < V4_THREAD; ++k) tv[k] = tg[base + k * TPB];

    Acc a{0.f, 0.f, 0.f, 0.f, 0.f};
    #pragma unroll
    for (int k = 0; k < V4_THREAD; ++k) {
        acc1(xv[k].x, tv[k].x, a); acc1(xv[k].y, tv[k].y, a);
        acc1(xv[k].z, tv[k].z, a); acc1(xv[k].w, tv[k].w, a);
    }
    waveReduce5(a);

    __shared__ float red[TPB / 64][5];
    const int wave = tid >> 6;
    if ((tid & 63) == 0) {
        red[wave][0] = a.sp; red[wave][1] = a.pt; red[wave][2] = a.st;
        red[wave][3] = a.sd; red[wave][4] = a.sdt;
    }
    __syncthreads();
    if (tid < 5) {
        float v = 0.f;
        #pragma unroll
        for (int w = 0; w < TPB / 64; ++w) v += red[w][tid];
        ws[tid * NBLK + blk] = v;
    }
}

// Stage 2: one block. Phase A: 240 threads fold one (comp, slice) run of
// 64 contiguous floats. Phase B: 48 threads compute dice/mse. Phase C:
// serial fixed-order 48-add on thread 0 (deterministic).
__global__ __launch_bounds__(TPB) void stage2(const float* __restrict__ ws,
                                              float* __restrict__ out) {
    const int tid = (int)threadIdx.x;
    __shared__ float fin[5][SLICES];
    if (tid < 5 * SLICES) {                    // 240 threads
        const int comp = tid / SLICES;
        const int s    = tid % SLICES;
        const float4* p = (const float4*)(ws + comp * NBLK + s * BPS);
        float4 a4 = {0.f, 0.f, 0.f, 0.f};
        #pragma unroll
        for (int k = 0; k < BPS / 4; ++k) {
            float4 v = p[k];
            a4.x += v.x; a4.y += v.y; a4.z += v.z; a4.w += v.w;
        }
        fin[comp][s] = (a4.x + a4.y) + (a4.z + a4.w);
    }
    __syncthreads();
    __shared__ float dice_s[SLICES], mse_s[SLICES];
    if (tid < SLICES) {
        float sp = fin[0][tid], pt = fin[1][tid], st = fin[2][tid];
        float sd = fin[3][tid], sdt = fin[4][tid];
        dice_s[tid] = (2.0f * pt + SMOOTHF) / (sp + st + SMOOTHF);
        float cp = st, cn = (float)ELEMS - st;
        float s1 = sdt, s0 = sd - sdt;
        float mp = (cp > 0.f) ? s1 / fmaxf(cp, 1.f) : 0.f;
        float mn = (cn > 0.f) ? s0 / fmaxf(cn, 1.f) : 0.f;
        mse_s[tid] = mp + mn;
    }
    __syncthreads();
    if (tid == 0) {
        float dice = 0.f, mse = 0.f;
        #pragma unroll
        for (int s = 0; s < SLICES; ++s) { dice += dice_s[s]; mse += mse_s[s]; }
        float dice_loss = 1.0f - dice / (float)SLICES;   // == Σ_c(1-mean_b)/C
        float mse_loss  = mse / (float)SLICES;           // == Σ/(B·C)
        out[0] = DICE_WF * dice_loss + (1.0f - DICE_WF) * mse_loss;
    }
}

extern "C" void kernel_launch(void* const* d_in, const int* in_sizes, int n_in,
                              void* d_out, int out_size, void* d_ws, size_t ws_size,
                              hipStream_t stream) {
    const float4* lg = (const float4*)d_in[0];
    const float4* tg = (const float4*)d_in[1];
    float* out = (float*)d_out;
    float* ws  = (float*)d_ws;   // 60 KB scratch, fully rewritten each call
    stage1<<<NBLK, TPB, 0, stream>>>(lg, tg, ws);
    stage2<<<1, TPB, 0, stream>>>(ws, out);
}